// Round 5
// baseline (468.142 us; speedup 1.0000x reference)
//
#include <hip/hip_runtime.h>
#include <hip/hip_bf16.h>

#define NN 32
#define CC 16
#define HH 256
#define WW 256
#define HWSZ (HH * WW)

// Bucketing geometry: key = n(5b) | ytile(3b) | xtile(4b) -> 4096 buckets.
// Bucket table footprint = (16+1) x (32+1) px * 32 B ~= 18 KB -> L2-resident.
#define XTS 4                       // x >> 4 : 16 x-tiles
#define YTS 5                       // y >> 5 : 8 y-tiles
#define NBUCK (NN * (WW >> XTS) * (HH >> YTS))   // 4096
#define BPAD 768                    // mean 488, +12 sigma -> overflow prob ~0

typedef float f32x4 __attribute__((ext_vector_type(4)));

// ---------- Transpose + downconvert: NCHW fp32 -> NHWC bf16 (into ws) ----------
__global__ __launch_bounds__(256) void nchw_to_nhwc_bf16_kernel(
    const float* __restrict__ inp,
    __hip_bfloat16* __restrict__ dst)
{
    int t = blockIdx.x * blockDim.x + threadIdx.x;   // 0 .. N*H*W/4 - 1
    int pix = t * 4;
    int x = pix & (WW - 1);
    int y = (pix >> 8) & (HH - 1);
    int n = pix >> 16;

    const float* src = inp + (size_t)n * CC * HWSZ + y * WW + x;
    f32x4 v[CC];
#pragma unroll
    for (int c = 0; c < CC; ++c)
        v[c] = __builtin_nontemporal_load((const f32x4*)(src + (size_t)c * HWSZ));

#pragma unroll
    for (int j = 0; j < 4; ++j) {
        union {
            __hip_bfloat16 h[CC];
            uint4 q[2];
        } u;
        const float* vf = (const float*)v;
#pragma unroll
        for (int c = 0; c < CC; ++c)
            u.h[c] = __float2bfloat16(vf[4 * c + j]);
        uint4* d = (uint4*)(dst + (size_t)(pix + j) * CC);
        d[0] = u.q[0];
        d[1] = u.q[1];
    }
}

// ---------- Zero bucket cursors (part of the graph; runs each replay) ----------
__global__ __launch_bounds__(256) void zero_cursors_kernel(int* __restrict__ cur)
{
    int i = blockIdx.x * blockDim.x + threadIdx.x;
    if (i < NBUCK) cur[i] = 0;
}

// ---------- Scatter points into (image, tile) buckets ----------
// Record = 16 B {gx, gy, orig_p, n}; position via device-scope atomicAdd.
__global__ __launch_bounds__(256) void scatter_kernel(
    const float* __restrict__ grid,
    const int*   __restrict__ idx,
    uint4*       __restrict__ rec,
    int*         __restrict__ cur,
    int P)
{
    int p = blockIdx.x * blockDim.x + threadIdx.x;
    if (p >= P) return;

    float2 g = ((const float2*)grid)[p];
    int n = idx[p];

    float x = (g.x + 1.0f) * 0.5f * (float)(WW - 1);
    float y = (g.y + 1.0f) * 0.5f * (float)(HH - 1);
    int x0 = (int)floorf(x);
    int y0 = (int)floorf(y);
    int xc = min(max(x0, 0), WW - 1);
    int yc = min(max(y0, 0), HH - 1);

    int key = (n << 7) | ((yc >> YTS) << XTS) | (xc >> XTS);
    int pos = atomicAdd(&cur[key], 1);
    if (pos < BPAD)
        rec[(size_t)key * BPAD + pos] =
            make_uint4(__float_as_uint(g.x), __float_as_uint(g.y),
                       (unsigned)p, (unsigned)n);
}

// ---------- Sample from NHWC bf16, one block per bucket ----------
// All gathers of a block land in an ~18 KB region -> L2-hits after first
// touch, heavy lane-level line sharing. Output = full 64-B line per point.
__global__ __launch_bounds__(256) void sample_bucketed_kernel(
    const __hip_bfloat16* __restrict__ src,    // NHWC bf16
    const uint4* __restrict__ rec,
    const int*   __restrict__ cur,
    float*       __restrict__ out)
{
    int bucket = blockIdx.x;
    int cnt = min(cur[bucket], BPAD);
    const uint4* brec = rec + (size_t)bucket * BPAD;

    for (int i = threadIdx.x; i < cnt; i += 256) {
        uint4 r = brec[i];
        float gx = __uint_as_float(r.x);
        float gy = __uint_as_float(r.y);
        int p = (int)r.z;
        int n = (int)r.w;

        float x = (gx + 1.0f) * 0.5f * (float)(WW - 1);
        float y = (gy + 1.0f) * 0.5f * (float)(HH - 1);

        float x0f = floorf(x), y0f = floorf(y);
        float wx = x - x0f, wy = y - y0f;
        int x0 = (int)x0f, y0 = (int)y0f;
        int x1 = x0 + 1, y1 = y0 + 1;

        float vx0 = (x0 >= 0 && x0 <= WW - 1) ? 1.0f : 0.0f;
        float vx1 = (x1 >= 0 && x1 <= WW - 1) ? 1.0f : 0.0f;
        float vy0 = (y0 >= 0 && y0 <= HH - 1) ? 1.0f : 0.0f;
        float vy1 = (y1 >= 0 && y1 <= HH - 1) ? 1.0f : 0.0f;

        int x0c = min(max(x0, 0), WW - 1);
        int x1c = min(max(x1, 0), WW - 1);
        int y0c = min(max(y0, 0), HH - 1);
        int y1c = min(max(y1, 0), HH - 1);

        float w00 = (1.0f - wx) * (1.0f - wy) * vx0 * vy0;
        float w01 = wx * (1.0f - wy) * vx1 * vy0;
        float w10 = (1.0f - wx) * wy * vx0 * vy1;
        float w11 = wx * wy * vx1 * vy1;

        const __hip_bfloat16* base = src + (size_t)n * (size_t)(HWSZ * CC);
        const uint4* c00 = (const uint4*)(base + (uint32_t)(y0c * WW + x0c) * CC);
        const uint4* c01 = (const uint4*)(base + (uint32_t)(y0c * WW + x1c) * CC);
        const uint4* c10 = (const uint4*)(base + (uint32_t)(y1c * WW + x0c) * CC);
        const uint4* c11 = (const uint4*)(base + (uint32_t)(y1c * WW + x1c) * CC);

        uint4 q0 = c00[0];
        uint4 q1 = c00[1];
        uint4 q2 = c01[0];
        uint4 q3 = c01[1];
        uint4 q4 = c10[0];
        uint4 q5 = c10[1];
        uint4 q6 = c11[0];
        uint4 q7 = c11[1];

        float res[CC];
#pragma unroll
        for (int k = 0; k < CC; ++k) res[k] = 0.0f;

        auto acc = [&](uint4 a, uint4 bq, float w) {
            uint32_t u[8] = {a.x, a.y, a.z, a.w, bq.x, bq.y, bq.z, bq.w};
#pragma unroll
            for (int k = 0; k < 8; ++k) {
                __hip_bfloat162 h2 = *reinterpret_cast<__hip_bfloat162*>(&u[k]);
                float2 f = __bfloat1622float2(h2);
                res[2 * k + 0] += f.x * w;
                res[2 * k + 1] += f.y * w;
            }
        };

        acc(q0, q1, w00);
        acc(q2, q3, w01);
        acc(q4, q5, w10);
        acc(q6, q7, w11);

        float4* outv = (float4*)(out + (size_t)p * CC);
#pragma unroll
        for (int k = 0; k < 4; ++k)
            outv[k] = make_float4(res[4 * k + 0], res[4 * k + 1],
                                  res[4 * k + 2], res[4 * k + 3]);
    }
}

// ---------- Mid fallback: round-4 sample (table fits ws, no bucket space) ----
__global__ __launch_bounds__(256) void sample_nhwc_bf16_kernel(
    const __hip_bfloat16* __restrict__ src,
    const float* __restrict__ grid,
    const int*   __restrict__ idx,
    float*       __restrict__ out,
    int P)
{
    int p = blockIdx.x * blockDim.x + threadIdx.x;
    if (p >= P) return;

    float2 g = ((const float2*)grid)[p];
    int b = idx[p];

    float x = (g.x + 1.0f) * 0.5f * (float)(WW - 1);
    float y = (g.y + 1.0f) * 0.5f * (float)(HH - 1);

    float x0f = floorf(x), y0f = floorf(y);
    float wx = x - x0f, wy = y - y0f;
    int x0 = (int)x0f, y0 = (int)y0f;
    int x1 = x0 + 1, y1 = y0 + 1;

    float vx0 = (x0 >= 0 && x0 <= WW - 1) ? 1.0f : 0.0f;
    float vx1 = (x1 >= 0 && x1 <= WW - 1) ? 1.0f : 0.0f;
    float vy0 = (y0 >= 0 && y0 <= HH - 1) ? 1.0f : 0.0f;
    float vy1 = (y1 >= 0 && y1 <= HH - 1) ? 1.0f : 0.0f;

    int x0c = min(max(x0, 0), WW - 1);
    int x1c = min(max(x1, 0), WW - 1);
    int y0c = min(max(y0, 0), HH - 1);
    int y1c = min(max(y1, 0), HH - 1);

    float w00 = (1.0f - wx) * (1.0f - wy) * vx0 * vy0;
    float w01 = wx * (1.0f - wy) * vx1 * vy0;
    float w10 = (1.0f - wx) * wy * vx0 * vy1;
    float w11 = wx * wy * vx1 * vy1;

    const __hip_bfloat16* base = src + (size_t)b * (size_t)(HWSZ * CC);
    const uint4* c00 = (const uint4*)(base + (uint32_t)(y0c * WW + x0c) * CC);
    const uint4* c01 = (const uint4*)(base + (uint32_t)(y0c * WW + x1c) * CC);
    const uint4* c10 = (const uint4*)(base + (uint32_t)(y1c * WW + x0c) * CC);
    const uint4* c11 = (const uint4*)(base + (uint32_t)(y1c * WW + x1c) * CC);

    uint4 q0 = c00[0], q1 = c00[1], q2 = c01[0], q3 = c01[1];
    uint4 q4 = c10[0], q5 = c10[1], q6 = c11[0], q7 = c11[1];

    float res[CC];
#pragma unroll
    for (int i = 0; i < CC; ++i) res[i] = 0.0f;

    auto acc = [&](uint4 a, uint4 bq, float w) {
        uint32_t u[8] = {a.x, a.y, a.z, a.w, bq.x, bq.y, bq.z, bq.w};
#pragma unroll
        for (int i = 0; i < 8; ++i) {
            __hip_bfloat162 h2 = *reinterpret_cast<__hip_bfloat162*>(&u[i]);
            float2 f = __bfloat1622float2(h2);
            res[2 * i + 0] += f.x * w;
            res[2 * i + 1] += f.y * w;
        }
    };

    acc(q0, q1, w00);
    acc(q2, q3, w01);
    acc(q4, q5, w10);
    acc(q6, q7, w11);

    float4* outv = (float4*)(out + (size_t)p * CC);
#pragma unroll
    for (int i = 0; i < 4; ++i)
        outv[i] = make_float4(res[4 * i + 0], res[4 * i + 1],
                              res[4 * i + 2], res[4 * i + 3]);
}

// ---------- Last fallback (NCHW direct, no workspace needed) ----------
__global__ __launch_bounds__(256) void sample_nchw_kernel(
    const float* __restrict__ inp,
    const float* __restrict__ grid,
    const int*   __restrict__ idx,
    float*       __restrict__ out,
    int P)
{
    int p = blockIdx.x * blockDim.x + threadIdx.x;
    if (p >= P) return;

    float2 g = ((const float2*)grid)[p];
    float x = (g.x + 1.0f) * 0.5f * (float)(WW - 1);
    float y = (g.y + 1.0f) * 0.5f * (float)(HH - 1);

    float x0f = floorf(x), y0f = floorf(y);
    float wx = x - x0f, wy = y - y0f;
    int x0 = (int)x0f, y0 = (int)y0f, x1 = x0 + 1, y1 = y0 + 1;

    float vx0 = (x0 >= 0 && x0 <= WW - 1) ? 1.0f : 0.0f;
    float vx1 = (x1 >= 0 && x1 <= WW - 1) ? 1.0f : 0.0f;
    float vy0 = (y0 >= 0 && y0 <= HH - 1) ? 1.0f : 0.0f;
    float vy1 = (y1 >= 0 && y1 <= HH - 1) ? 1.0f : 0.0f;

    int x0c = min(max(x0, 0), WW - 1);
    int x1c = min(max(x1, 0), WW - 1);
    int y0c = min(max(y0, 0), HH - 1);
    int y1c = min(max(y1, 0), HH - 1);

    float w00 = (1.0f - wx) * (1.0f - wy) * vx0 * vy0;
    float w01 = wx * (1.0f - wy) * vx1 * vy0;
    float w10 = (1.0f - wx) * wy * vx0 * vy1;
    float w11 = wx * wy * vx1 * vy1;

    const float* base = inp + (size_t)idx[p] * (size_t)(CC * HWSZ);
    int o00 = y0c * WW + x0c, o01 = y0c * WW + x1c;
    int o10 = y1c * WW + x0c, o11 = y1c * WW + x1c;

    float res[CC];
#pragma unroll
    for (int c = 0; c < CC; ++c) {
        const float* bsrc = base + c * HWSZ;
        res[c] = bsrc[o00] * w00 + bsrc[o01] * w01 + bsrc[o10] * w10 + bsrc[o11] * w11;
    }
    float4* outv = (float4*)(out + (size_t)p * CC);
#pragma unroll
    for (int i = 0; i < 4; ++i)
        outv[i] = make_float4(res[4 * i], res[4 * i + 1], res[4 * i + 2], res[4 * i + 3]);
}

extern "C" void kernel_launch(void* const* d_in, const int* in_sizes, int n_in,
                              void* d_out, int out_size, void* d_ws, size_t ws_size,
                              hipStream_t stream) {
    const float* inp  = (const float*)d_in[0];
    const float* grid = (const float*)d_in[1];
    const int*   idx  = (const int*)d_in[2];
    float* out = (float*)d_out;

    int P = in_sizes[2];

    const size_t table_bytes = (size_t)NN * CC * HWSZ * sizeof(__hip_bfloat16);  // 64 MiB
    const size_t rec_bytes   = (size_t)NBUCK * BPAD * sizeof(uint4);             // ~50 MiB
    const size_t cur_bytes   = (size_t)NBUCK * sizeof(int);                      // 16 KiB
    const size_t full_bytes  = table_bytes + rec_bytes + cur_bytes + 256;

    int tquads = NN * HH * WW / 4;

    if (ws_size >= full_bytes) {
        char* ws = (char*)d_ws;
        __hip_bfloat16* nhwc = (__hip_bfloat16*)ws;
        uint4* rec = (uint4*)(ws + table_bytes);
        int*   cur = (int*)(ws + table_bytes + rec_bytes);

        zero_cursors_kernel<<<(NBUCK + 255) / 256, 256, 0, stream>>>(cur);
        nchw_to_nhwc_bf16_kernel<<<tquads / 256, 256, 0, stream>>>(inp, nhwc);
        scatter_kernel<<<(P + 255) / 256, 256, 0, stream>>>(grid, idx, rec, cur, P);
        sample_bucketed_kernel<<<NBUCK, 256, 0, stream>>>(nhwc, rec, cur, out);
    } else if (ws_size >= table_bytes) {
        __hip_bfloat16* nhwc = (__hip_bfloat16*)d_ws;
        nchw_to_nhwc_bf16_kernel<<<tquads / 256, 256, 0, stream>>>(inp, nhwc);
        sample_nhwc_bf16_kernel<<<(P + 255) / 256, 256, 0, stream>>>(nhwc, grid, idx, out, P);
    } else {
        sample_nchw_kernel<<<(P + 255) / 256, 256, 0, stream>>>(inp, grid, idx, out, P);
    }
}

// Round 6
// 367.900 us; speedup vs baseline: 1.2725x; 1.2725x over previous
//
#include <hip/hip_runtime.h>
#include <hip/hip_bf16.h>

#define NN 32
#define CC 16
#define HH 256
#define WW 256
#define HWSZ (HH * WW)

typedef float f32x4 __attribute__((ext_vector_type(4)));

// ---------- Transpose + downconvert: NCHW fp32 -> NHWC bf16 (into ws) ----------
// 4 consecutive x-pixels per thread: float4 reads per channel (coalesced),
// 128 B contiguous bf16 write per thread. Input read exactly once -> nt loads.
__global__ __launch_bounds__(256) void nchw_to_nhwc_bf16_kernel(
    const float* __restrict__ inp,
    __hip_bfloat16* __restrict__ dst)
{
    int t = blockIdx.x * blockDim.x + threadIdx.x;   // 0 .. N*H*W/4 - 1
    int pix = t * 4;
    int x = pix & (WW - 1);
    int y = (pix >> 8) & (HH - 1);
    int n = pix >> 16;

    const float* src = inp + (size_t)n * CC * HWSZ + y * WW + x;
    f32x4 v[CC];
#pragma unroll
    for (int c = 0; c < CC; ++c)
        v[c] = __builtin_nontemporal_load((const f32x4*)(src + (size_t)c * HWSZ));

#pragma unroll
    for (int j = 0; j < 4; ++j) {
        union {
            __hip_bfloat16 h[CC];
            uint4 q[2];
        } u;
        const float* vf = (const float*)v;
#pragma unroll
        for (int c = 0; c < CC; ++c)
            u.h[c] = __float2bfloat16(vf[4 * c + j]);
        uint4* d = (uint4*)(dst + (size_t)(pix + j) * CC);
        d[0] = u.q[0];
        d[1] = u.q[1];
    }
}

// ---------- Sample from NHWC bf16, y-banded two-pass ----------
// Round-4 kernel with ONE change: each dispatch only processes points whose
// y0 row falls in a 128-row band (band = y0c >> 7). Per pass the gather hot
// set is a 32-MB half-table, which stays resident in the 256-MB Infinity
// Cache even under the output write stream (round-4 FETCH=311MB of a 384MB
// zero-reuse floor showed the full 64-MB table does NOT stay resident).
// Cost: grid/idx read twice (~24 MB) + one extra dispatch.
__global__ __launch_bounds__(256) void sample_nhwc_band_kernel(
    const __hip_bfloat16* __restrict__ src,    // NHWC bf16
    const float* __restrict__ grid,
    const int*   __restrict__ idx,
    float*       __restrict__ out,
    int P, int band)
{
    int p = blockIdx.x * blockDim.x + threadIdx.x;
    if (p >= P) return;

    float2 g = ((const float2*)grid)[p];
    float x = (g.x + 1.0f) * 0.5f * (float)(WW - 1);
    float y = (g.y + 1.0f) * 0.5f * (float)(HH - 1);

    float x0f = floorf(x);
    float y0f = floorf(y);

    int y0 = (int)y0f;
    int y0c = min(max(y0, 0), HH - 1);
    if ((y0c >> 7) != band) return;          // other pass handles this point

    int b = idx[p];

    float wx = x - x0f;
    float wy = y - y0f;

    int x0 = (int)x0f;
    int x1 = x0 + 1, y1 = y0 + 1;

    float vx0 = (x0 >= 0 && x0 <= WW - 1) ? 1.0f : 0.0f;
    float vx1 = (x1 >= 0 && x1 <= WW - 1) ? 1.0f : 0.0f;
    float vy0 = (y0 >= 0 && y0 <= HH - 1) ? 1.0f : 0.0f;
    float vy1 = (y1 >= 0 && y1 <= HH - 1) ? 1.0f : 0.0f;

    int x0c = min(max(x0, 0), WW - 1);
    int x1c = min(max(x1, 0), WW - 1);
    int y1c = min(max(y1, 0), HH - 1);

    float w00 = (1.0f - wx) * (1.0f - wy) * vx0 * vy0;
    float w01 = wx * (1.0f - wy) * vx1 * vy0;
    float w10 = (1.0f - wx) * wy * vx0 * vy1;
    float w11 = wx * wy * vx1 * vy1;

    const __hip_bfloat16* base = src + (size_t)b * (size_t)(HWSZ * CC);
    const uint4* c00 = (const uint4*)(base + (uint32_t)(y0c * WW + x0c) * CC);
    const uint4* c01 = (const uint4*)(base + (uint32_t)(y0c * WW + x1c) * CC);
    const uint4* c10 = (const uint4*)(base + (uint32_t)(y1c * WW + x0c) * CC);
    const uint4* c11 = (const uint4*)(base + (uint32_t)(y1c * WW + x1c) * CC);

    uint4 q0 = c00[0], q1 = c00[1], q2 = c01[0], q3 = c01[1];
    uint4 q4 = c10[0], q5 = c10[1], q6 = c11[0], q7 = c11[1];

    float res[CC];
#pragma unroll
    for (int i = 0; i < CC; ++i) res[i] = 0.0f;

    auto acc = [&](uint4 a, uint4 bq, float w) {
        uint32_t u[8] = {a.x, a.y, a.z, a.w, bq.x, bq.y, bq.z, bq.w};
#pragma unroll
        for (int i = 0; i < 8; ++i) {
            __hip_bfloat162 h2 = *reinterpret_cast<__hip_bfloat162*>(&u[i]);
            float2 f = __bfloat1622float2(h2);
            res[2 * i + 0] += f.x * w;
            res[2 * i + 1] += f.y * w;
        }
    };

    acc(q0, q1, w00);
    acc(q2, q3, w01);
    acc(q4, q5, w10);
    acc(q6, q7, w11);

    float4* outv = (float4*)(out + (size_t)p * CC);
#pragma unroll
    for (int i = 0; i < 4; ++i)
        outv[i] = make_float4(res[4 * i + 0], res[4 * i + 1],
                              res[4 * i + 2], res[4 * i + 3]);
}

// ---------- Last fallback (NCHW direct, no workspace needed) ----------
__global__ __launch_bounds__(256) void sample_nchw_kernel(
    const float* __restrict__ inp,
    const float* __restrict__ grid,
    const int*   __restrict__ idx,
    float*       __restrict__ out,
    int P)
{
    int p = blockIdx.x * blockDim.x + threadIdx.x;
    if (p >= P) return;

    float2 g = ((const float2*)grid)[p];
    float x = (g.x + 1.0f) * 0.5f * (float)(WW - 1);
    float y = (g.y + 1.0f) * 0.5f * (float)(HH - 1);

    float x0f = floorf(x), y0f = floorf(y);
    float wx = x - x0f, wy = y - y0f;
    int x0 = (int)x0f, y0 = (int)y0f, x1 = x0 + 1, y1 = y0 + 1;

    float vx0 = (x0 >= 0 && x0 <= WW - 1) ? 1.0f : 0.0f;
    float vx1 = (x1 >= 0 && x1 <= WW - 1) ? 1.0f : 0.0f;
    float vy0 = (y0 >= 0 && y0 <= HH - 1) ? 1.0f : 0.0f;
    float vy1 = (y1 >= 0 && y1 <= HH - 1) ? 1.0f : 0.0f;

    int x0c = min(max(x0, 0), WW - 1);
    int x1c = min(max(x1, 0), WW - 1);
    int y0c = min(max(y0, 0), HH - 1);
    int y1c = min(max(y1, 0), HH - 1);

    float w00 = (1.0f - wx) * (1.0f - wy) * vx0 * vy0;
    float w01 = wx * (1.0f - wy) * vx1 * vy0;
    float w10 = (1.0f - wx) * wy * vx0 * vy1;
    float w11 = wx * wy * vx1 * vy1;

    const float* base = inp + (size_t)idx[p] * (size_t)(CC * HWSZ);
    int o00 = y0c * WW + x0c, o01 = y0c * WW + x1c;
    int o10 = y1c * WW + x0c, o11 = y1c * WW + x1c;

    float res[CC];
#pragma unroll
    for (int c = 0; c < CC; ++c) {
        const float* bsrc = base + c * HWSZ;
        res[c] = bsrc[o00] * w00 + bsrc[o01] * w01 + bsrc[o10] * w10 + bsrc[o11] * w11;
    }
    float4* outv = (float4*)(out + (size_t)p * CC);
#pragma unroll
    for (int i = 0; i < 4; ++i)
        outv[i] = make_float4(res[4 * i], res[4 * i + 1], res[4 * i + 2], res[4 * i + 3]);
}

extern "C" void kernel_launch(void* const* d_in, const int* in_sizes, int n_in,
                              void* d_out, int out_size, void* d_ws, size_t ws_size,
                              hipStream_t stream) {
    const float* inp  = (const float*)d_in[0];
    const float* grid = (const float*)d_in[1];
    const int*   idx  = (const int*)d_in[2];
    float* out = (float*)d_out;

    int P = in_sizes[2];
    const size_t needed = (size_t)NN * CC * HWSZ * sizeof(__hip_bfloat16);  // 64 MiB

    if (ws_size >= needed) {
        __hip_bfloat16* nhwc = (__hip_bfloat16*)d_ws;
        int tquads = NN * HH * WW / 4;
        nchw_to_nhwc_bf16_kernel<<<tquads / 256, 256, 0, stream>>>(inp, nhwc);
        int blocks = (P + 255) / 256;
        sample_nhwc_band_kernel<<<blocks, 256, 0, stream>>>(nhwc, grid, idx, out, P, 0);
        sample_nhwc_band_kernel<<<blocks, 256, 0, stream>>>(nhwc, grid, idx, out, P, 1);
    } else {
        sample_nchw_kernel<<<(P + 255) / 256, 256, 0, stream>>>(inp, grid, idx, out, P);
    }
}